// Round 3
// baseline (290.792 us; speedup 1.0000x reference)
//
#include <hip/hip_runtime.h>
#include <math.h>

// Problem shape (fixed by reference setup_inputs):
//   B=32, H=64, W=64, C=256, NHWC layout (C contiguous).
//   Outputs: x (B,H,W,C) fp32 then gate (B,1,1,C) fp32, concatenated flat.
#define B_ 32
#define HW_ 4096          // 64*64
#define C_ 256
#define C4_ 64            // C/4
#define NCHUNK 64         // spatial chunks per batch in pass 1 (was 32)
#define CHUNK 64          // HW_/NCHUNK positions per chunk
#define PPT 16            // positions per thread = CHUNK/4

// Native vector type — required for __builtin_nontemporal_store (HIP's
// float4 is a class and is rejected by the builtin).
typedef float vfloat4 __attribute__((ext_vector_type(4)));

// ---------------- Kernel 1: partial reduction + fused per-batch gate ----------------
// Grid: B*NCHUNK = 2048 blocks, 256 threads. Thread layout: t = pg*64 + c4,
// pg in [0,4) position-group, c4 in [0,64) float4 channel group.
//
// Round-2 post-mortem: pool was ~72 us vs a 21 us HBM floor — MLP-starved.
// 6.3 TB/s x ~900 ns latency needs ~5.7 MB in flight; 1024 blocks x
// unroll-8 had ~0.5 MB. Fix: 2048 blocks (8192 waves = full machine) and
// all 16 loads per thread issued as one static batch before any
// accumulation (v[16] fully unrolled -> stays in VGPRs, ~6x in-flight).
//
// Gate fusion (validated round 2): partials are written with AGENT-scope
// relaxed atomic stores (coherent at L3, no buffer_wbl2 — round 1's
// __threadfence() L2-flush storm cost 190 us), wave 0 drains with
// s_waitcnt vmcnt(0), bumps counters[b] agent-scope; last arriver reads
// partials back agent-scope and computes the gate for batch b.
__global__ __launch_bounds__(256) void pool_gate_kernel(
    const float* __restrict__ in, float* __restrict__ ws_sum,
    float* __restrict__ ws_max, unsigned int* __restrict__ counters,
    const float* __restrict__ factor, const float* __restrict__ W1,
    const float* __restrict__ b1, const float* __restrict__ gamma,
    const float* __restrict__ beta, const float* __restrict__ bn_mean,
    const float* __restrict__ bn_var, const float* __restrict__ Wg,
    const float* __restrict__ bg, const float* __restrict__ gumbel,
    float* __restrict__ ws_gate, float* __restrict__ out_gate) {
  const int b = blockIdx.x >> 6;   // / NCHUNK
  const int k = blockIdx.x & 63;   // % NCHUNK
  const int t = threadIdx.x;
  const int c4 = t & 63;
  const int pg = t >> 6;           // 0..3 == wave id

  const float4* in4 = (const float4*)in;
  // float4 index of (b, pos = k*CHUNK + pg, channel-group c4)
  long base = (long)b * (HW_ * C4_) + (long)(k * CHUNK + pg) * C4_ + c4;

  // Issue ALL 16 loads (independent, static indices -> registers) before
  // any accumulation: 256 B in flight per thread.
  float4 v[PPT];
#pragma unroll
  for (int i = 0; i < PPT; ++i) v[i] = in4[base + (long)i * (4 * C4_)];

  // Pairwise tree reduction (shorter dep chains than serial).
  float4 s = make_float4(0.f, 0.f, 0.f, 0.f);
  float4 m = make_float4(-INFINITY, -INFINITY, -INFINITY, -INFINITY);
#pragma unroll
  for (int i = 0; i < PPT / 2; ++i) {
    float4 a = v[2 * i], c = v[2 * i + 1];
    s.x += a.x + c.x; s.y += a.y + c.y;
    s.z += a.z + c.z; s.w += a.w + c.w;
    m.x = fmaxf(m.x, fmaxf(a.x, c.x)); m.y = fmaxf(m.y, fmaxf(a.y, c.y));
    m.z = fmaxf(m.z, fmaxf(a.z, c.z)); m.w = fmaxf(m.w, fmaxf(a.w, c.w));
  }

  __shared__ float4 ssum[256];
  __shared__ float4 smax[256];
  __shared__ int winner_s;
  ssum[t] = s;
  smax[t] = m;
  __syncthreads();

  if (pg == 0) {  // wave 0 only (t == lane, 0..63)
#pragma unroll
    for (int q = 1; q < 4; ++q) {
      float4 s2 = ssum[q * 64 + c4];
      float4 m2 = smax[q * 64 + c4];
      s.x += s2.x; s.y += s2.y; s.z += s2.z; s.w += s2.w;
      m.x = fmaxf(m.x, m2.x); m.y = fmaxf(m.y, m2.y);
      m.z = fmaxf(m.z, m2.z); m.w = fmaxf(m.w, m2.w);
    }
    // Agent-scope (device-coherent) stores of this chunk's partials: visible
    // at the coherence point once vmcnt retires — no cache flush needed.
    const int o = ((b * NCHUNK + k) * C4_ + c4) * 4;
    __hip_atomic_store(&ws_sum[o + 0], s.x, __ATOMIC_RELAXED, __HIP_MEMORY_SCOPE_AGENT);
    __hip_atomic_store(&ws_sum[o + 1], s.y, __ATOMIC_RELAXED, __HIP_MEMORY_SCOPE_AGENT);
    __hip_atomic_store(&ws_sum[o + 2], s.z, __ATOMIC_RELAXED, __HIP_MEMORY_SCOPE_AGENT);
    __hip_atomic_store(&ws_sum[o + 3], s.w, __ATOMIC_RELAXED, __HIP_MEMORY_SCOPE_AGENT);
    __hip_atomic_store(&ws_max[o + 0], m.x, __ATOMIC_RELAXED, __HIP_MEMORY_SCOPE_AGENT);
    __hip_atomic_store(&ws_max[o + 1], m.y, __ATOMIC_RELAXED, __HIP_MEMORY_SCOPE_AGENT);
    __hip_atomic_store(&ws_max[o + 2], m.z, __ATOMIC_RELAXED, __HIP_MEMORY_SCOPE_AGENT);
    __hip_atomic_store(&ws_max[o + 3], m.w, __ATOMIC_RELAXED, __HIP_MEMORY_SCOPE_AGENT);
    // Drain wave 0's stores to the coherence point, THEN bump the counter.
    asm volatile("s_waitcnt vmcnt(0)" ::: "memory");
    if (t == 0) {
      unsigned prev = __hip_atomic_fetch_add(&counters[b], 1u,
                                             __ATOMIC_RELAXED,
                                             __HIP_MEMORY_SCOPE_AGENT);
      winner_s = (prev == NCHUNK - 1) ? 1 : 0;
    }
  }
  __syncthreads();
  if (!winner_s) return;

  // ---------------- fused gate computation (last block of batch b) ----------------
  const int j = t;  // channel

  float sj = 0.f;
  float mj = -INFINITY;
#pragma unroll 8
  for (int kk = 0; kk < NCHUNK; ++kk) {
    // Agent-scope loads: bypass this XCD's (possibly stale) L2.
    float ps = __hip_atomic_load(&ws_sum[(b * NCHUNK + kk) * C_ + j],
                                 __ATOMIC_RELAXED, __HIP_MEMORY_SCOPE_AGENT);
    float pm = __hip_atomic_load(&ws_max[(b * NCHUNK + kk) * C_ + j],
                                 __ATOMIC_RELAXED, __HIP_MEMORY_SCOPE_AGENT);
    sj += ps;
    mj = fmaxf(mj, pm);
  }

  // softmax over the 2 blend factors
  float a0 = factor[0], a1 = factor[1];
  float mx = fmaxf(a0, a1);
  float e0 = expf(a0 - mx), e1 = expf(a1 - mx);
  float inv = 1.f / (e0 + e1);
  float f0 = e0 * inv, f1 = e1 * inv;

  __shared__ float pool[C_];
  pool[j] = (sj * (1.0f / (float)HW_)) * f0 + mj * f1;
  __syncthreads();

  // h[j] = sum_c pool[c] * W1[c,j] + b1[j]; 4 independent FMA chains for ILP
  float h0 = 0.f, h1 = 0.f, h2 = 0.f, h3 = 0.f;
#pragma unroll 8
  for (int c = 0; c < C_; c += 4) {
    h0 = fmaf(pool[c + 0], W1[(c + 0) * C_ + j], h0);
    h1 = fmaf(pool[c + 1], W1[(c + 1) * C_ + j], h1);
    h2 = fmaf(pool[c + 2], W1[(c + 2) * C_ + j], h2);
    h3 = fmaf(pool[c + 3], W1[(c + 3) * C_ + j], h3);
  }
  float h = ((h0 + h1) + (h2 + h3)) + b1[j];
  // BatchNorm (inference) + ReLU
  h = gamma[j] * (h - bn_mean[j]) * rsqrtf(bn_var[j] + 1e-3f) + beta[j];
  h = fmaxf(h, 0.f);

  // grouped 1x1 conv -> 2 logits, + gumbel; hard sample = argmax
  float z0 = fmaf(h, Wg[j * 2 + 0], bg[j * 2 + 0]) + gumbel[(b * C_ + j) * 2 + 0];
  float z1 = fmaf(h, Wg[j * 2 + 1], bg[j * 2 + 1]) + gumbel[(b * C_ + j) * 2 + 1];
  // argmax picks index 0 on ties -> gate = 1 iff z1 > z0 strictly
  float g = (z1 > z0) ? 1.0f : 0.0f;

  ws_gate[b * C_ + j] = g;
  out_gate[b * C_ + j] = g;
}

// ---------------- Kernel 2: x = inputs * gate[b,c] ----------------
// 8192 blocks x 256 threads; ~5.8 TB/s combined (46 us, round-1 inference)
// — near the mixed read+NT-write ceiling; unchanged.
__global__ __launch_bounds__(256) void apply_gate_kernel(
    const float* __restrict__ in, const float* __restrict__ ws_gate,
    float* __restrict__ out) {
  const vfloat4* in4 = (const vfloat4*)in;
  const vfloat4* g4 = (const vfloat4*)ws_gate;
  vfloat4* out4 = (vfloat4*)out;

  const int t = threadIdx.x;
  const int lane = t & 63;   // channel-group c4
  const int grp = t >> 6;    // 0..3

  // Block covers 1024 consecutive float4s = 16 positions x 64 channel-groups.
  long base = (long)blockIdx.x * 1024;
  long i0 = base + (long)grp * 256 + lane;  // then +64, +128, +192

  int b = (int)(base >> 18);  // 2^18 float4s per batch; constant per block
  vfloat4 g = g4[b * C4_ + lane];

  vfloat4 v0 = in4[i0];
  vfloat4 v1 = in4[i0 + 64];
  vfloat4 v2 = in4[i0 + 128];
  vfloat4 v3 = in4[i0 + 192];

  v0 *= g;
  v1 *= g;
  v2 *= g;
  v3 *= g;

  __builtin_nontemporal_store(v0, &out4[i0]);
  __builtin_nontemporal_store(v1, &out4[i0 + 64]);
  __builtin_nontemporal_store(v2, &out4[i0 + 128]);
  __builtin_nontemporal_store(v3, &out4[i0 + 192]);
}

extern "C" void kernel_launch(void* const* d_in, const int* in_sizes, int n_in,
                              void* d_out, int out_size, void* d_ws, size_t ws_size,
                              hipStream_t stream) {
  const float* inputs  = (const float*)d_in[0];
  const float* factor  = (const float*)d_in[1];
  const float* W1      = (const float*)d_in[2];
  const float* b1      = (const float*)d_in[3];
  const float* gamma   = (const float*)d_in[4];
  const float* beta    = (const float*)d_in[5];
  const float* bn_mean = (const float*)d_in[6];
  const float* bn_var  = (const float*)d_in[7];
  const float* Wg      = (const float*)d_in[8];
  const float* bg      = (const float*)d_in[9];
  const float* gumbel  = (const float*)d_in[10];

  float* out_x = (float*)d_out;                          // B*H*W*C floats
  float* out_gate = (float*)d_out + (long)B_ * HW_ * C_; // B*C floats

  // Workspace layout (floats):
  float* ws_sum  = (float*)d_ws;                   // B*NCHUNK*C = 524288
  float* ws_max  = ws_sum + B_ * NCHUNK * C_;      // 524288
  float* ws_gate = ws_max + B_ * NCHUNK * C_;      // B*C = 8192
  unsigned int* counters = (unsigned int*)(ws_gate + B_ * C_);  // B uints

  // Workspace is poisoned between iterations -> counters must be zeroed.
  // 128-byte async memset is graph-capturable (stream memset node).
  hipMemsetAsync(counters, 0, B_ * sizeof(unsigned int), stream);

  pool_gate_kernel<<<B_ * NCHUNK, 256, 0, stream>>>(
      inputs, ws_sum, ws_max, counters, factor, W1, b1, gamma, beta, bn_mean,
      bn_var, Wg, bg, gumbel, ws_gate, out_gate);

  const long n4 = (long)B_ * HW_ * C4_;  // 2^23 float4s
  apply_gate_kernel<<<(int)(n4 / 1024), 256, 0, stream>>>(inputs, ws_gate, out_x);
}

// Round 4
// 281.812 us; speedup vs baseline: 1.0319x; 1.0319x over previous
//
#include <hip/hip_runtime.h>
#include <math.h>

// Problem shape (fixed by reference setup_inputs):
//   B=32, H=64, W=64, C=256, NHWC layout (C contiguous).
//   Outputs: x (B,H,W,C) fp32 then gate (B,1,1,C) fp32, concatenated flat.
#define B_ 32
#define HW_ 4096          // 64*64
#define C_ 256
#define C4_ 64            // C/4
#define NCHUNK 32         // spatial chunks per batch in pass 1 (reverted from 64)
#define CHUNK 128         // HW_/NCHUNK positions per chunk

// Native vector type — required for __builtin_nontemporal_store (HIP's
// float4 is a class and is rejected by the builtin).
typedef float vfloat4 __attribute__((ext_vector_type(4)));

// ---------------- Kernel 1: partial reduction + fused per-batch gate ----------------
// Grid: B*NCHUNK = 1024 blocks, 256 threads. Thread layout: t = pg*64 + c4,
// pg in [0,4) position-group, c4 in [0,64) float4 channel group.
//
// Round-3 post-mortem (MODEL): MI355X load throughput is capped by
// outstanding-miss tracking, not HBM BW: ~128 lines/CU x 64B x 256 CU /
// ~900ns = ~2.3 TB/s read ceiling (fills hit 6.7 TB/s because stores are
// fire-and-forget; m13 copy reads = 3.15; apply reads = 2.9; pool = 2.3).
// Pool's main phase (~55 us for 134 MB) is therefore AT the read roofline
// for plain loads — the round-2/3 MLP restructurings were chasing a
// non-bottleneck. This round reverts to the proven round-0 streaming loop
// (NCHUNK=32) and shaves the winner-tail (full unroll -> ~2 latency rounds
// instead of 8 for its 64 independent agent-scope loads).
//
// Gate fusion (validated round 2): partials are written with AGENT-scope
// relaxed atomic stores (coherent at L3, no buffer_wbl2 — round 1's
// __threadfence() L2-flush storm cost 190 us), wave 0 drains with
// s_waitcnt vmcnt(0), bumps counters[b] agent-scope; last arriver reads
// partials back agent-scope and computes the gate for batch b.
__global__ __launch_bounds__(256) void pool_gate_kernel(
    const float* __restrict__ in, float* __restrict__ ws_sum,
    float* __restrict__ ws_max, unsigned int* __restrict__ counters,
    const float* __restrict__ factor, const float* __restrict__ W1,
    const float* __restrict__ b1, const float* __restrict__ gamma,
    const float* __restrict__ beta, const float* __restrict__ bn_mean,
    const float* __restrict__ bn_var, const float* __restrict__ Wg,
    const float* __restrict__ bg, const float* __restrict__ gumbel,
    float* __restrict__ ws_gate, float* __restrict__ out_gate) {
  const int b = blockIdx.x >> 5;   // / NCHUNK
  const int k = blockIdx.x & 31;   // % NCHUNK
  const int t = threadIdx.x;
  const int c4 = t & 63;
  const int pg = t >> 6;           // 0..3 == wave id

  const float4* in4 = (const float4*)in;
  // float4 index of (b, pos = k*CHUNK + pg, channel-group c4)
  long base = (long)b * (HW_ * C4_) + (long)(k * CHUNK + pg) * C4_ + c4;

  // Round-0 proven streaming loop: 32 float4 loads, unroll 8.
  float4 s = make_float4(0.f, 0.f, 0.f, 0.f);
  float4 m = make_float4(-INFINITY, -INFINITY, -INFINITY, -INFINITY);
#pragma unroll 8
  for (int p = 0; p < CHUNK; p += 4) {
    float4 v = in4[base + (long)p * C4_];
    s.x += v.x; s.y += v.y; s.z += v.z; s.w += v.w;
    m.x = fmaxf(m.x, v.x); m.y = fmaxf(m.y, v.y);
    m.z = fmaxf(m.z, v.z); m.w = fmaxf(m.w, v.w);
  }

  __shared__ float4 ssum[256];
  __shared__ float4 smax[256];
  __shared__ int winner_s;
  ssum[t] = s;
  smax[t] = m;
  __syncthreads();

  if (pg == 0) {  // wave 0 only (t == lane, 0..63)
#pragma unroll
    for (int q = 1; q < 4; ++q) {
      float4 s2 = ssum[q * 64 + c4];
      float4 m2 = smax[q * 64 + c4];
      s.x += s2.x; s.y += s2.y; s.z += s2.z; s.w += s2.w;
      m.x = fmaxf(m.x, m2.x); m.y = fmaxf(m.y, m2.y);
      m.z = fmaxf(m.z, m2.z); m.w = fmaxf(m.w, m2.w);
    }
    // Agent-scope (device-coherent) stores of this chunk's partials: visible
    // at the coherence point once vmcnt retires — no cache flush needed.
    const int o = ((b * NCHUNK + k) * C4_ + c4) * 4;
    __hip_atomic_store(&ws_sum[o + 0], s.x, __ATOMIC_RELAXED, __HIP_MEMORY_SCOPE_AGENT);
    __hip_atomic_store(&ws_sum[o + 1], s.y, __ATOMIC_RELAXED, __HIP_MEMORY_SCOPE_AGENT);
    __hip_atomic_store(&ws_sum[o + 2], s.z, __ATOMIC_RELAXED, __HIP_MEMORY_SCOPE_AGENT);
    __hip_atomic_store(&ws_sum[o + 3], s.w, __ATOMIC_RELAXED, __HIP_MEMORY_SCOPE_AGENT);
    __hip_atomic_store(&ws_max[o + 0], m.x, __ATOMIC_RELAXED, __HIP_MEMORY_SCOPE_AGENT);
    __hip_atomic_store(&ws_max[o + 1], m.y, __ATOMIC_RELAXED, __HIP_MEMORY_SCOPE_AGENT);
    __hip_atomic_store(&ws_max[o + 2], m.z, __ATOMIC_RELAXED, __HIP_MEMORY_SCOPE_AGENT);
    __hip_atomic_store(&ws_max[o + 3], m.w, __ATOMIC_RELAXED, __HIP_MEMORY_SCOPE_AGENT);
    // Drain wave 0's stores to the coherence point, THEN bump the counter.
    asm volatile("s_waitcnt vmcnt(0)" ::: "memory");
    if (t == 0) {
      unsigned prev = __hip_atomic_fetch_add(&counters[b], 1u,
                                             __ATOMIC_RELAXED,
                                             __HIP_MEMORY_SCOPE_AGENT);
      winner_s = (prev == NCHUNK - 1) ? 1 : 0;
    }
  }
  __syncthreads();
  if (!winner_s) return;

  // ---------------- fused gate computation (last block of batch b) ----------------
  const int j = t;  // channel

  // 64 independent agent-scope loads, FULLY unrolled so the compiler can
  // batch-issue them (~2 latency rounds instead of 8 with unroll-8).
  float sj = 0.f;
  float mj = -INFINITY;
#pragma unroll
  for (int kk = 0; kk < NCHUNK; ++kk) {
    // Agent-scope loads: bypass this XCD's (possibly stale) L2.
    float ps = __hip_atomic_load(&ws_sum[(b * NCHUNK + kk) * C_ + j],
                                 __ATOMIC_RELAXED, __HIP_MEMORY_SCOPE_AGENT);
    float pm = __hip_atomic_load(&ws_max[(b * NCHUNK + kk) * C_ + j],
                                 __ATOMIC_RELAXED, __HIP_MEMORY_SCOPE_AGENT);
    sj += ps;
    mj = fmaxf(mj, pm);
  }

  // softmax over the 2 blend factors
  float a0 = factor[0], a1 = factor[1];
  float mx = fmaxf(a0, a1);
  float e0 = expf(a0 - mx), e1 = expf(a1 - mx);
  float inv = 1.f / (e0 + e1);
  float f0 = e0 * inv, f1 = e1 * inv;

  __shared__ float pool[C_];
  pool[j] = (sj * (1.0f / (float)HW_)) * f0 + mj * f1;
  __syncthreads();

  // h[j] = sum_c pool[c] * W1[c,j] + b1[j]; 4 independent FMA chains for ILP
  float h0 = 0.f, h1 = 0.f, h2 = 0.f, h3 = 0.f;
#pragma unroll 8
  for (int c = 0; c < C_; c += 4) {
    h0 = fmaf(pool[c + 0], W1[(c + 0) * C_ + j], h0);
    h1 = fmaf(pool[c + 1], W1[(c + 1) * C_ + j], h1);
    h2 = fmaf(pool[c + 2], W1[(c + 2) * C_ + j], h2);
    h3 = fmaf(pool[c + 3], W1[(c + 3) * C_ + j], h3);
  }
  float h = ((h0 + h1) + (h2 + h3)) + b1[j];
  // BatchNorm (inference) + ReLU
  h = gamma[j] * (h - bn_mean[j]) * rsqrtf(bn_var[j] + 1e-3f) + beta[j];
  h = fmaxf(h, 0.f);

  // grouped 1x1 conv -> 2 logits, + gumbel; hard sample = argmax
  float z0 = fmaf(h, Wg[j * 2 + 0], bg[j * 2 + 0]) + gumbel[(b * C_ + j) * 2 + 0];
  float z1 = fmaf(h, Wg[j * 2 + 1], bg[j * 2 + 1]) + gumbel[(b * C_ + j) * 2 + 1];
  // argmax picks index 0 on ties -> gate = 1 iff z1 > z0 strictly
  float g = (z1 > z0) ? 1.0f : 0.0f;

  ws_gate[b * C_ + j] = g;
  out_gate[b * C_ + j] = g;
}

// ---------------- Kernel 2: x = inputs * gate[b,c] ----------------
// 8192 blocks x 256 threads; 134R+134W in ~46 us (~2.9 TB/s read) — at the
// read-rate cap; unchanged.
__global__ __launch_bounds__(256) void apply_gate_kernel(
    const float* __restrict__ in, const float* __restrict__ ws_gate,
    float* __restrict__ out) {
  const vfloat4* in4 = (const vfloat4*)in;
  const vfloat4* g4 = (const vfloat4*)ws_gate;
  vfloat4* out4 = (vfloat4*)out;

  const int t = threadIdx.x;
  const int lane = t & 63;   // channel-group c4
  const int grp = t >> 6;    // 0..3

  // Block covers 1024 consecutive float4s = 16 positions x 64 channel-groups.
  long base = (long)blockIdx.x * 1024;
  long i0 = base + (long)grp * 256 + lane;  // then +64, +128, +192

  int b = (int)(base >> 18);  // 2^18 float4s per batch; constant per block
  vfloat4 g = g4[b * C4_ + lane];

  vfloat4 v0 = in4[i0];
  vfloat4 v1 = in4[i0 + 64];
  vfloat4 v2 = in4[i0 + 128];
  vfloat4 v3 = in4[i0 + 192];

  v0 *= g;
  v1 *= g;
  v2 *= g;
  v3 *= g;

  __builtin_nontemporal_store(v0, &out4[i0]);
  __builtin_nontemporal_store(v1, &out4[i0 + 64]);
  __builtin_nontemporal_store(v2, &out4[i0 + 128]);
  __builtin_nontemporal_store(v3, &out4[i0 + 192]);
}

extern "C" void kernel_launch(void* const* d_in, const int* in_sizes, int n_in,
                              void* d_out, int out_size, void* d_ws, size_t ws_size,
                              hipStream_t stream) {
  const float* inputs  = (const float*)d_in[0];
  const float* factor  = (const float*)d_in[1];
  const float* W1      = (const float*)d_in[2];
  const float* b1      = (const float*)d_in[3];
  const float* gamma   = (const float*)d_in[4];
  const float* beta    = (const float*)d_in[5];
  const float* bn_mean = (const float*)d_in[6];
  const float* bn_var  = (const float*)d_in[7];
  const float* Wg      = (const float*)d_in[8];
  const float* bg      = (const float*)d_in[9];
  const float* gumbel  = (const float*)d_in[10];

  float* out_x = (float*)d_out;                          // B*H*W*C floats
  float* out_gate = (float*)d_out + (long)B_ * HW_ * C_; // B*C floats

  // Workspace layout (floats):
  float* ws_sum  = (float*)d_ws;                   // B*NCHUNK*C = 262144
  float* ws_max  = ws_sum + B_ * NCHUNK * C_;      // 262144
  float* ws_gate = ws_max + B_ * NCHUNK * C_;      // B*C = 8192
  unsigned int* counters = (unsigned int*)(ws_gate + B_ * C_);  // B uints

  // Workspace is poisoned between iterations -> counters must be zeroed.
  // 128-byte async memset is graph-capturable (stream memset node).
  hipMemsetAsync(counters, 0, B_ * sizeof(unsigned int), stream);

  pool_gate_kernel<<<B_ * NCHUNK, 256, 0, stream>>>(
      inputs, ws_sum, ws_max, counters, factor, W1, b1, gamma, beta, bn_mean,
      bn_var, Wg, bg, gumbel, ws_gate, out_gate);

  const long n4 = (long)B_ * HW_ * C4_;  // 2^23 float4s
  apply_gate_kernel<<<(int)(n4 / 1024), 256, 0, stream>>>(inputs, ws_gate, out_x);
}

// Round 6
// 281.053 us; speedup vs baseline: 1.0346x; 1.0027x over previous
//
#include <hip/hip_runtime.h>
#include <math.h>

// Problem shape (fixed by reference setup_inputs):
//   B=32, H=64, W=64, C=256, NHWC layout (C contiguous).
//   Outputs: x (B,H,W,C) fp32 then gate (B,1,1,C) fp32, concatenated flat.
#define B_ 32
#define HW_ 4096          // 64*64
#define C_ 256
#define C4_ 64            // C/4
#define KPB 16            // blocks (chunks) per batch
#define POS 256           // positions per block
#define RR 50             // rows held in registers per thread (200 VGPRs)
#define LR 14             // rows held in LDS per thread (14*4KB = 56KB/block)

// Native vector type — required for __builtin_nontemporal_store (HIP's
// float4 is a class and is rejected by the builtin).
typedef float vfloat4 __attribute__((ext_vector_type(4)));

__device__ inline vfloat4 vmax4(vfloat4 a, vfloat4 b) {
  vfloat4 r;
  r.x = fmaxf(a.x, b.x); r.y = fmaxf(a.y, b.y);
  r.z = fmaxf(a.z, b.z); r.w = fmaxf(a.w, b.w);
  return r;
}

// ---------------- Single-pass fused kernel ----------------
// The 2-pass structure reads the input TWICE (pool + apply), each pass at
// its read-rate ceiling. This reads ONCE: block (b,k) owns 256 positions
// (256 KB), retains them on-chip (50 rows/thread in VGPRs + 14 in LDS),
// syncs for the gate, multiplies, NT-stores.
//
// __launch_bounds__(256,2) + 64KB static LDS => 2 blocks/CU => all 512
// blocks co-resident BY CONSTRUCTION => intra-grid sync cannot deadlock.
//
// Sync protocol (validated rounds 2-4 — NO __threadfence, which triggers a
// ~190us buffer_wbl2 L2-flush storm on gfx950): AGENT-scope relaxed atomic
// stores (coherent at L3, no flush) + per-wave s_waitcnt vmcnt(0) drain +
// agent-scope counter bump; last arriver computes the gate.
//
// ROUND-5 BUG (absmax 4.84 = |x|, i.e. wrong 0/1 gate): the winner
// published the gate with all 4 waves, drained with a PER-WAVE vmcnt(0),
// and t0 (wave 0) set flags[b] while waves 1-3's gate stores (channels
// 64..255) were still in flight -> siblings read stale gates. FIX: a
// __syncthreads() between the per-wave drains and the flag store — every
// wave drains BEFORE the barrier, so the flag happens-after all 256
// channels are at the coherence point.
//
// Thread layout: t = pg*64 + c4; row i (i=0..63) is position p = 4*i+pg;
// lanes = 64 consecutive float4 channel-groups -> 1KB coalesced/row.
__global__ __launch_bounds__(256, 2) void fused_gate_kernel(
    const float* __restrict__ in, float* __restrict__ ws_sum,
    float* __restrict__ ws_max, float* __restrict__ ws_gate,
    unsigned int* __restrict__ counters, unsigned int* __restrict__ flags,
    const float* __restrict__ factor, const float* __restrict__ W1,
    const float* __restrict__ b1, const float* __restrict__ gamma,
    const float* __restrict__ beta, const float* __restrict__ bn_mean,
    const float* __restrict__ bn_var, const float* __restrict__ Wg,
    const float* __restrict__ bg, const float* __restrict__ gumbel,
    float* __restrict__ out_x, float* __restrict__ out_gate) {
  const int blk = blockIdx.x;
  const int b = blk >> 4;          // / KPB
  const int k = blk & 15;          // % KPB
  const int t = threadIdx.x;
  const int c4 = t & 63;
  const int pg = t >> 6;           // 0..3 == wave id

  // Static LDS, exactly 64 KB:
  //   s_data[14*256] : retained rows        (57344 B)
  //   s_red[512]     : cross-wave reduce    ( 8192 B)
  // Overlays inside s_red (all placed where the reduce never reads, or
  // dead after it; every cross-use is fenced by __syncthreads):
  //   flag slot  = ((int*)&s_red[1])   (s_red[1] never read by reduce)
  //   poolv[256] = (float*)&s_red[64]  (red_s[64..127] dead after reduce)
  //   gatev[256] = (float*)&s_red[128]
  __shared__ vfloat4 s_data[LR * 256];
  __shared__ vfloat4 s_red[512];
  vfloat4* red_s = s_red;          // [256] sums
  vfloat4* red_m = s_red + 256;    // [256] maxes
  int*   wflag = (int*)&s_red[1];
  float* poolv = (float*)&s_red[64];
  float* gatev = (float*)&s_red[128];

  const vfloat4* in4 = (const vfloat4*)in;
  vfloat4* out4 = (vfloat4*)out_x;
  const long base = (long)b * (HW_ * C4_) + (long)(k * POS + pg) * C4_ + c4;

  // ---- Phase 1: single read of this block's 256 KB; retain on-chip ----
  vfloat4 vr[RR];
#pragma unroll
  for (int i = 0; i < RR; ++i) vr[i] = in4[base + (long)(i * 4) * C4_];

  vfloat4 s = {0.f, 0.f, 0.f, 0.f};
  vfloat4 m = {-INFINITY, -INFINITY, -INFINITY, -INFINITY};
#pragma unroll
  for (int i = 0; i < LR; ++i) {
    vfloat4 v = in4[base + (long)((RR + i) * 4) * C4_];
    s_data[i * 256 + pg * 64 + c4] = v;
    s += v;
    m = vmax4(m, v);
  }
#pragma unroll
  for (int i = 0; i < RR; ++i) { s += vr[i]; m = vmax4(m, vr[i]); }

  // ---- Phase 2: cross-wave reduce, publish chunk partial ----
  red_s[t] = s;
  red_m[t] = m;
  __syncthreads();

  if (pg == 0) {  // wave 0 only (t == c4) — per-wave drain is sufficient here
#pragma unroll
    for (int q = 1; q < 4; ++q) {
      s += red_s[q * 64 + c4];
      m = vmax4(m, red_m[q * 64 + c4]);
    }
    // Agent-scope stores: coherent at L3 once vmcnt retires, no L2 flush.
    const int o = ((b * KPB + k) * C4_ + c4) * 4;
    __hip_atomic_store(&ws_sum[o + 0], s.x, __ATOMIC_RELAXED, __HIP_MEMORY_SCOPE_AGENT);
    __hip_atomic_store(&ws_sum[o + 1], s.y, __ATOMIC_RELAXED, __HIP_MEMORY_SCOPE_AGENT);
    __hip_atomic_store(&ws_sum[o + 2], s.z, __ATOMIC_RELAXED, __HIP_MEMORY_SCOPE_AGENT);
    __hip_atomic_store(&ws_sum[o + 3], s.w, __ATOMIC_RELAXED, __HIP_MEMORY_SCOPE_AGENT);
    __hip_atomic_store(&ws_max[o + 0], m.x, __ATOMIC_RELAXED, __HIP_MEMORY_SCOPE_AGENT);
    __hip_atomic_store(&ws_max[o + 1], m.y, __ATOMIC_RELAXED, __HIP_MEMORY_SCOPE_AGENT);
    __hip_atomic_store(&ws_max[o + 2], m.z, __ATOMIC_RELAXED, __HIP_MEMORY_SCOPE_AGENT);
    __hip_atomic_store(&ws_max[o + 3], m.w, __ATOMIC_RELAXED, __HIP_MEMORY_SCOPE_AGENT);
    asm volatile("s_waitcnt vmcnt(0)" ::: "memory");  // drain, THEN bump
    if (t == 0) {
      unsigned prev = __hip_atomic_fetch_add(&counters[b], 1u,
                                             __ATOMIC_RELAXED,
                                             __HIP_MEMORY_SCOPE_AGENT);
      *wflag = (prev == KPB - 1) ? 1 : 0;
    }
  }
  __syncthreads();
  const int winner = *wflag;  // block-uniform
  __syncthreads();

  vfloat4 g4v;
  if (winner) {
    // ---- Phase 3w: last block of batch b computes the gate ----
    const int j = t;  // channel
    float sj = 0.f;
    float mj = -INFINITY;
#pragma unroll
    for (int kk = 0; kk < KPB; ++kk) {
      float ps = __hip_atomic_load(&ws_sum[(b * KPB + kk) * C_ + j],
                                   __ATOMIC_RELAXED, __HIP_MEMORY_SCOPE_AGENT);
      float pm = __hip_atomic_load(&ws_max[(b * KPB + kk) * C_ + j],
                                   __ATOMIC_RELAXED, __HIP_MEMORY_SCOPE_AGENT);
      sj += ps;
      mj = fmaxf(mj, pm);
    }

    // softmax over the 2 blend factors
    float a0 = factor[0], a1 = factor[1];
    float mx = fmaxf(a0, a1);
    float e0 = expf(a0 - mx), e1 = expf(a1 - mx);
    float inv = 1.f / (e0 + e1);
    float f0 = e0 * inv, f1 = e1 * inv;

    poolv[j] = (sj * (1.0f / (float)HW_)) * f0 + mj * f1;
    __syncthreads();

    // h[j] = sum_c pool[c] * W1[c,j] + b1[j]; 4 FMA chains for ILP
    float h0 = 0.f, h1 = 0.f, h2 = 0.f, h3 = 0.f;
#pragma unroll 8
    for (int c = 0; c < C_; c += 4) {
      h0 = fmaf(poolv[c + 0], W1[(c + 0) * C_ + j], h0);
      h1 = fmaf(poolv[c + 1], W1[(c + 1) * C_ + j], h1);
      h2 = fmaf(poolv[c + 2], W1[(c + 2) * C_ + j], h2);
      h3 = fmaf(poolv[c + 3], W1[(c + 3) * C_ + j], h3);
    }
    float h = ((h0 + h1) + (h2 + h3)) + b1[j];
    // BatchNorm (inference) + ReLU
    h = gamma[j] * (h - bn_mean[j]) * rsqrtf(bn_var[j] + 1e-3f) + beta[j];
    h = fmaxf(h, 0.f);

    // grouped 1x1 conv -> 2 logits, + gumbel; gate = 1 iff z1 > z0
    float z0 = fmaf(h, Wg[j * 2 + 0], bg[j * 2 + 0]) + gumbel[(b * C_ + j) * 2 + 0];
    float z1 = fmaf(h, Wg[j * 2 + 1], bg[j * 2 + 1]) + gumbel[(b * C_ + j) * 2 + 1];
    float g = (z1 > z0) ? 1.0f : 0.0f;

    gatev[j] = g;
    out_gate[b * C_ + j] = g;
    __hip_atomic_store(&ws_gate[b * C_ + j], g, __ATOMIC_RELAXED,
                       __HIP_MEMORY_SCOPE_AGENT);
    // Each wave drains ITS OWN gate stores to the coherence point...
    asm volatile("s_waitcnt vmcnt(0)" ::: "memory");
    // ...then the block barrier guarantees ALL waves have drained (THE
    // round-5 race fix), and only then may t0 release the flag.
    __syncthreads();
    if (t == 0)
      __hip_atomic_store(&flags[b], 1u, __ATOMIC_RELAXED,
                         __HIP_MEMORY_SCOPE_AGENT);
    // gatev[] LDS writes are visible block-wide via the barrier above.
    g4v.x = gatev[c4 * 4 + 0];
    g4v.y = gatev[c4 * 4 + 1];
    g4v.z = gatev[c4 * 4 + 2];
    g4v.w = gatev[c4 * 4 + 3];
  } else {
    // ---- Phase 3s: siblings wait for the gate (all co-resident) ----
    if (t == 0) {
      while (__hip_atomic_load(&flags[b], __ATOMIC_RELAXED,
                               __HIP_MEMORY_SCOPE_AGENT) == 0u)
        __builtin_amdgcn_s_sleep(2);
    }
    __syncthreads();  // all threads ordered after t0's flag observation
    g4v.x = __hip_atomic_load(&ws_gate[b * C_ + c4 * 4 + 0], __ATOMIC_RELAXED, __HIP_MEMORY_SCOPE_AGENT);
    g4v.y = __hip_atomic_load(&ws_gate[b * C_ + c4 * 4 + 1], __ATOMIC_RELAXED, __HIP_MEMORY_SCOPE_AGENT);
    g4v.z = __hip_atomic_load(&ws_gate[b * C_ + c4 * 4 + 2], __ATOMIC_RELAXED, __HIP_MEMORY_SCOPE_AGENT);
    g4v.w = __hip_atomic_load(&ws_gate[b * C_ + c4 * 4 + 3], __ATOMIC_RELAXED, __HIP_MEMORY_SCOPE_AGENT);
  }

  // ---- Phase 4: multiply retained data by gate, NT-store ----
#pragma unroll
  for (int i = 0; i < RR; ++i) {
    vfloat4 v = vr[i] * g4v;
    __builtin_nontemporal_store(v, &out4[base + (long)(i * 4) * C4_]);
  }
#pragma unroll
  for (int i = 0; i < LR; ++i) {
    vfloat4 v = s_data[i * 256 + pg * 64 + c4] * g4v;
    __builtin_nontemporal_store(v, &out4[base + (long)((RR + i) * 4) * C4_]);
  }
}

extern "C" void kernel_launch(void* const* d_in, const int* in_sizes, int n_in,
                              void* d_out, int out_size, void* d_ws, size_t ws_size,
                              hipStream_t stream) {
  const float* inputs  = (const float*)d_in[0];
  const float* factor  = (const float*)d_in[1];
  const float* W1      = (const float*)d_in[2];
  const float* b1      = (const float*)d_in[3];
  const float* gamma   = (const float*)d_in[4];
  const float* beta    = (const float*)d_in[5];
  const float* bn_mean = (const float*)d_in[6];
  const float* bn_var  = (const float*)d_in[7];
  const float* Wg      = (const float*)d_in[8];
  const float* bg      = (const float*)d_in[9];
  const float* gumbel  = (const float*)d_in[10];

  float* out_x = (float*)d_out;                          // B*H*W*C floats
  float* out_gate = (float*)d_out + (long)B_ * HW_ * C_; // B*C floats

  // Workspace layout (floats):
  float* ws_sum  = (float*)d_ws;                   // B*KPB*C = 131072
  float* ws_max  = ws_sum + B_ * KPB * C_;         // 131072
  float* ws_gate = ws_max + B_ * KPB * C_;         // B*C = 8192
  unsigned int* counters = (unsigned int*)(ws_gate + B_ * C_);  // B uints
  unsigned int* flags    = counters + B_;                        // B uints

  // Workspace is poisoned between iterations -> counters+flags must be
  // zeroed. 256-byte async memset is graph-capturable (stream memset node).
  hipMemsetAsync(counters, 0, 2 * B_ * sizeof(unsigned int), stream);

  fused_gate_kernel<<<B_ * KPB, 256, 0, stream>>>(
      inputs, ws_sum, ws_max, ws_gate, counters, flags, factor, W1, b1,
      gamma, beta, bn_mean, bn_var, Wg, bg, gumbel, out_x, out_gate);
}